// Round 18
// baseline (159.035 us; speedup 1.0000x reference)
//
#include <hip/hip_runtime.h>
#include <hip/hip_bf16.h>

typedef __bf16 bf16x8 __attribute__((ext_vector_type(8)));
typedef __bf16 bf16x4 __attribute__((ext_vector_type(4)));
typedef float  f32x4  __attribute__((ext_vector_type(4)));

#define MFMA16(a,b,c) __builtin_amdgcn_mfma_f32_16x16x32_bf16((a),(b),(c),0,0,0)

#define T_SEQ 2048
#define CDIM  1024
#define NH    16
#define DH    64
#define C3    3072
#define QKS   2048   // qk buffer row stride: [q 1024 | k 1024]

// async global->LDS, 16B per lane; LDS dest must be wave-uniform base + lane*16
#define GLDS(g, l) __builtin_amdgcn_global_load_lds( \
    (const __attribute__((address_space(1))) void*)(g), \
    (__attribute__((address_space(3))) void*)(l), 16, 0, 0)

// ---------------- cast f32 -> bf16, vectorized ----------------
__global__ void cast_f32_bf16_kernel(const float* __restrict__ in,
                                     __bf16* __restrict__ out, int n4) {
  int i = blockIdx.x * 256 + threadIdx.x;
  if (i >= n4) return;
  f32x4 v = ((const f32x4*)in)[i];
  bf16x4 o;
  o[0] = (__bf16)v[0]; o[1] = (__bf16)v[1];
  o[2] = (__bf16)v[2]; o[3] = (__bf16)v[3];
  ((bf16x4*)out)[i] = o;
}

// ---- transpose + cast: W[R][C] f32 -> WT[C][R] bf16; rows c<qcols scaled ----
__global__ void transpose_cast_kernel(const float* __restrict__ W,
                                      __bf16* __restrict__ WT, int R, int C,
                                      float qscale, int qcols) {
  __shared__ float tile[32][33];
  int c0 = blockIdx.x * 32, r0 = blockIdx.y * 32;
  int tx = threadIdx.x, ty = threadIdx.y;
#pragma unroll
  for (int i = 0; i < 32; i += 8)
    tile[ty + i][tx] = W[(size_t)(r0 + ty + i) * C + c0 + tx];
  __syncthreads();
#pragma unroll
  for (int i = 0; i < 32; i += 8) {
    int c = c0 + ty + i;
    float sc = (c < qcols) ? qscale : 1.0f;
    WT[(size_t)c * R + r0 + tx] = (__bf16)(tile[tx][ty + i] * sc);
  }
}

// ------- GEMM1: 128x128 4-phase bf16 GEMM, 64KB LDS => 2 blocks/CU ---------
__global__ __launch_bounds__(256, 2)
void gemm1_kernel(const __bf16* __restrict__ A, const __bf16* __restrict__ BT,
                  __bf16* __restrict__ qkp, __bf16* __restrict__ VTp) {
  __shared__ __align__(16) __bf16 S[2][2][128 * 64];  // [buf][A/B] 64KB
  const int K = 1024;
  const int tid  = threadIdx.x;
  const int lane = tid & 63;
  const int g    = lane >> 4;
  const int l16  = lane & 15;
  const int wave = tid >> 6;
  const int wm   = wave >> 1;
  const int wn   = wave & 1;

  const int sb = (blockIdx.x & 7) * 192 + (blockIdx.x >> 3);
  const int bn = sb % 24;
  const int bm = sb / 24;

  const int srow = tid >> 3;
  const int scol = ((tid & 7) << 4) ^ ((srow & 7) << 4);
  const int swz  = (l16 & 7) << 4;

  const __bf16* Abase = A  + (size_t)(bm * 128 + srow) * K + (scol >> 1);
  const __bf16* Bbase = BT + (size_t)(bn * 128 + srow) * K + (scol >> 1);

  f32x4  acc[4][4] = {};
  bf16x8 ar[2][2];
  bf16x8 br[4][2];

#define STAGE_A(BUF, K0) do { \
    _Pragma("unroll") for (int u_ = 0; u_ < 4; ++u_) \
      GLDS(Abase + (size_t)u_ * 32 * K + (K0), (char*)&S[BUF][0][0] + u_ * 4096 + tid * 16); \
  } while (0)
#define STAGE_B(BUF, K0) do { \
    _Pragma("unroll") for (int u_ = 0; u_ < 4; ++u_) \
      GLDS(Bbase + (size_t)u_ * 32 * K + (K0), (char*)&S[BUF][1][0] + u_ * 4096 + tid * 16); \
  } while (0)

#define LDA(BUF, IH) do { \
    const char* ab_ = (const char*)&S[BUF][0][0]; \
    _Pragma("unroll") for (int i_ = 0; i_ < 2; ++i_) { \
      const char* rp_ = ab_ + (wm * 64 + (IH) * 32 + i_ * 16 + l16) * 128; \
      _Pragma("unroll") for (int kk_ = 0; kk_ < 2; ++kk_) \
        ar[i_][kk_] = *(const bf16x8*)(rp_ + ((kk_ * 64 + g * 16) ^ swz)); \
    } \
  } while (0)

#define LDB(BUF) do { \
    const char* bb_ = (const char*)&S[BUF][1][0]; \
    _Pragma("unroll") for (int j_ = 0; j_ < 4; ++j_) { \
      const char* rp_ = bb_ + (wn * 64 + j_ * 16 + l16) * 128; \
      _Pragma("unroll") for (int kk_ = 0; kk_ < 2; ++kk_) \
        br[j_][kk_] = *(const bf16x8*)(rp_ + ((kk_ * 64 + g * 16) ^ swz)); \
    } \
  } while (0)

#define MQ(IH) do { \
    __builtin_amdgcn_s_setprio(1); \
    _Pragma("unroll") for (int kk_ = 0; kk_ < 2; ++kk_) \
      _Pragma("unroll") for (int i_ = 0; i_ < 2; ++i_) \
        _Pragma("unroll") for (int j_ = 0; j_ < 4; ++j_) \
          acc[(IH) * 2 + i_][j_] = \
              MFMA16(ar[i_][kk_], br[j_][kk_], acc[(IH) * 2 + i_][j_]); \
    __builtin_amdgcn_s_setprio(0); \
  } while (0)

#define SBAR do { \
    __builtin_amdgcn_sched_barrier(0); \
    __builtin_amdgcn_s_barrier(); \
    __builtin_amdgcn_sched_barrier(0); \
  } while (0)

  STAGE_A(0, 0); STAGE_B(0, 0);
  asm volatile("s_waitcnt vmcnt(0)" ::: "memory");
  SBAR;

  const int NIT = K >> 7;
#pragma unroll 1
  for (int it = 0; it < NIT; ++it) {
    const int kt1 = (2 * it + 1) << 6;
    const int kt2 = (2 * it + 2) << 6;
    const bool stg = (it + 1) < NIT;

    LDA(0, 0); LDB(0);
    STAGE_A(1, kt1); STAGE_B(1, kt1);
    SBAR; MQ(0); SBAR;

    LDA(0, 1);
    asm volatile("s_waitcnt vmcnt(0)" ::: "memory");
    SBAR; MQ(1); SBAR;

    LDA(1, 0); LDB(1);
    if (stg) { STAGE_A(0, kt2); STAGE_B(0, kt2); }
    SBAR; MQ(0); SBAR;

    LDA(1, 1);
    asm volatile("s_waitcnt vmcnt(0)" ::: "memory");
    SBAR; MQ(1); SBAR;
  }

  if (bn < 16) {
#pragma unroll
    for (int a = 0; a < 4; ++a) {
      const int row0 = bm * 128 + wm * 64 + a * 16 + g * 4;
#pragma unroll
      for (int jj = 0; jj < 4; ++jj) {
        const int col = bn * 128 + wn * 64 + jj * 16 + l16;
#pragma unroll
        for (int r = 0; r < 4; ++r)
          qkp[(size_t)(row0 + r) * QKS + col] = (__bf16)acc[a][jj][r];
      }
    }
  } else {
#pragma unroll
    for (int a = 0; a < 4; ++a) {
      const int row0 = bm * 128 + wm * 64 + a * 16 + g * 4;
      const int b    = row0 >> 11;
      const int t0   = row0 & 2047;
#pragma unroll
      for (int jj = 0; jj < 4; ++jj) {
        const int c = (bn - 16) * 128 + wn * 64 + jj * 16 + l16;
        bf16x4 pb;
#pragma unroll
        for (int r = 0; r < 4; ++r) pb[r] = (__bf16)acc[a][jj][r];
        *(bf16x4*)(VTp + ((size_t)((b << 10) + c)) * T_SEQ + t0) = pb;
      }
    }
  }
#undef STAGE_A
#undef STAGE_B
#undef LDA
#undef LDB
#undef MQ
#undef SBAR
}

// ---------------- GEMM2: 256x128 4-phase bf16 GEMM, f32 out ----------------
__global__ __launch_bounds__(512, 1)
void gemm2_kernel(const __bf16* __restrict__ A, const __bf16* __restrict__ BT,
                  float* __restrict__ Cout) {
  __shared__ __align__(16) __bf16 S[2][3][128 * 64];  // [buf][A-lo,A-hi,B] 96KB
  const int tid  = threadIdx.x;
  const int lane = tid & 63;
  const int g    = lane >> 4;
  const int l16  = lane & 15;
  const int wave = tid >> 6;
  const int wm   = wave >> 2;
  const int wn   = wave & 3;

  const int K = 1024;
  const int sb = (blockIdx.x & 7) * 32 + (blockIdx.x >> 3);
  const int bn = sb & 7;
  const int bm = sb >> 3;

  const int srow = tid >> 3;
  const int scol = ((tid & 7) << 4) ^ ((srow & 7) << 4);
  const int swz  = (l16 & 7) << 4;

  const __bf16* Abase = A  + (size_t)(bm * 256 + srow) * K + (scol >> 1);
  const __bf16* Bbase = BT + (size_t)(bn * 128 + srow) * K + (scol >> 1);

  f32x4  acc[8][2] = {};
  bf16x8 ar[4][2];
  bf16x8 br[2][2];

#define STAGE2(BUF, U, K0) do { \
    const __bf16* sp_ = ((U) < 2 ? Abase + (size_t)(U) * 128 * K : Bbase) + (K0); \
    char* dp_ = (char*)&S[BUF][U][0] + tid * 16; \
    GLDS(sp_, dp_); \
    GLDS(sp_ + (size_t)64 * K, dp_ + 8192); \
  } while (0)

#define LDA2(BUF, MH) do { \
    const char* ab_ = (const char*)&S[BUF][wm][0]; \
    _Pragma("unroll") for (int i_ = 0; i_ < 4; ++i_) { \
      const char* rp_ = ab_ + ((MH) * 64 + i_ * 16 + l16) * 128; \
      _Pragma("unroll") for (int kk_ = 0; kk_ < 2; ++kk_) \
        ar[i_][kk_] = *(const bf16x8*)(rp_ + ((kk_ * 64 + g * 16) ^ swz)); \
    } \
  } while (0)

#define LDB2(BUF) do { \
    const char* bb_ = (const char*)&S[BUF][2][0]; \
    _Pragma("unroll") for (int j_ = 0; j_ < 2; ++j_) { \
      const char* rp_ = bb_ + (wn * 32 + j_ * 16 + l16) * 128; \
      _Pragma("unroll") for (int kk_ = 0; kk_ < 2; ++kk_) \
        br[j_][kk_] = *(const bf16x8*)(rp_ + ((kk_ * 64 + g * 16) ^ swz)); \
    } \
  } while (0)

#define MQ2(MH) do { \
    __builtin_amdgcn_s_setprio(1); \
    _Pragma("unroll") for (int kk_ = 0; kk_ < 2; ++kk_) \
      _Pragma("unroll") for (int i_ = 0; i_ < 4; ++i_) \
        _Pragma("unroll") for (int j_ = 0; j_ < 2; ++j_) \
          acc[(MH) * 4 + i_][j_] = \
              MFMA16(ar[i_][kk_], br[j_][kk_], acc[(MH) * 4 + i_][j_]); \
    __builtin_amdgcn_s_setprio(0); \
  } while (0)

#define SBAR2 do { \
    __builtin_amdgcn_sched_barrier(0); \
    __builtin_amdgcn_s_barrier(); \
    __builtin_amdgcn_sched_barrier(0); \
  } while (0)

  STAGE2(0, 0, 0); STAGE2(0, 1, 0); STAGE2(0, 2, 0);
  STAGE2(1, 0, 64);
  asm volatile("s_waitcnt vmcnt(2)" ::: "memory");
  SBAR2;

  const int NIT = K >> 7;
#pragma unroll 1
  for (int it = 0; it < NIT; ++it) {
    const int k1 = (2 * it + 1) << 6;
    const int k2 = (2 * it + 2) << 6;
    const int k3 = (2 * it + 3) << 6;
    const bool stg = (it + 1) < NIT;

    LDA2(0, 0); LDB2(0);
    STAGE2(1, 1, k1); STAGE2(1, 2, k1);
    SBAR2; MQ2(0); SBAR2;

    LDA2(0, 1);
    if (stg) {
      STAGE2(0, 0, k2);
      asm volatile("s_waitcnt vmcnt(2)" ::: "memory");
    } else {
      asm volatile("s_waitcnt vmcnt(0)" ::: "memory");
    }
    SBAR2; MQ2(1); SBAR2;

    LDA2(1, 0); LDB2(1);
    if (stg) { STAGE2(0, 1, k2); STAGE2(0, 2, k2); }
    SBAR2; MQ2(0); SBAR2;

    LDA2(1, 1);
    if (stg) {
      STAGE2(1, 0, k3);
      asm volatile("s_waitcnt vmcnt(2)" ::: "memory");
    }
    SBAR2; MQ2(1); SBAR2;
  }

#pragma unroll
  for (int ii = 0; ii < 8; ++ii) {
    const int row0 = bm * 256 + wm * 128 + ii * 16 + g * 4;
#pragma unroll
    for (int jj = 0; jj < 2; ++jj) {
      const int col = bn * 128 + wn * 32 + jj * 16 + l16;
#pragma unroll
      for (int r = 0; r < 4; ++r)
        Cout[(size_t)(row0 + r) * 1024 + col] = acc[ii][jj][r];
    }
  }
#undef STAGE2
#undef LDA2
#undef LDB2
#undef MQ2
#undef SBAR2
}

// ------- causal flash attention, QBLK=128, UNPAIRED descending blocks ------
// One block per (bh, qtile): 1024 blocks, 48KB LDS -> 3 blocks/CU resident
// with scheduler backfill (was 512 blocks = 2/CU lockstep pairs). Decode
// qt = 15 - (bid>>6): longest blocks (32 KV-tiles) dispatch first, 2-tile
// blocks backfill the tail. bh = bid&63 keeps bid%8 = bh%8 (XCD locality).
__global__ __launch_bounds__(256)
void attn_kernel(const __bf16* __restrict__ qk, const __bf16* __restrict__ VT,
                 __bf16* __restrict__ y) {
  __shared__ __align__(16) __bf16 Klds[2][64 * 64];
  __shared__ __align__(16) __bf16 Vlds[2][64 * 64];
  __shared__ __align__(16) __bf16 Plds[4][32 * 64];
  const int tid  = threadIdx.x;
  const int lane = tid & 63;
  const int g    = lane >> 4;
  const int l16  = lane & 15;
  const int wave = tid >> 6;

  const int qt = 15 - (blockIdx.x >> 6);   // descending work order
  const int bh = blockIdx.x & 63;          // XCD-local decode
  const int h  = bh & (NH - 1);
  const int b  = bh >> 4;

  const __bf16* Qg = qk + (size_t)b * T_SEQ * QKS + h * DH;
  const __bf16* Kg = Qg + 1024;
  const __bf16* Vt = VT + ((size_t)(b << 10) + h * DH) * T_SEQ;

  const int srow = tid >> 3;
  const int scol = ((tid & 7) * 16) ^ ((srow & 7) << 4);
  const int swz  = (l16 & 7) << 4;

  const float NEG = -3.0e38f;

  bf16x8 ones;
#pragma unroll
  for (int j = 0; j < 8; ++j) ones[j] = (__bf16)1.0f;

  char* Pw = (char*)&Plds[wave][0];   // [32 q][64 kv] slab, rows 128B

  const int qbase = qt * 128 + wave * 32;   // wave's first q row

  bf16x8 qf[2][2];
#pragma unroll
  for (int qg = 0; qg < 2; ++qg)
#pragma unroll
    for (int kk = 0; kk < 2; ++kk)
      qf[qg][kk] = *(const bf16x8*)(Qg + (size_t)(qbase + qg * 16 + l16) * QKS + kk * 32 + g * 8);

  f32x4 o[2][4] = {};
  f32x4 o_l[2]  = {};

  const int nkb = 2 * qt + 2;
  {   // prologue: stage tile 0 into buffer 0
    const __bf16* ksrc = Kg + (size_t)srow * QKS + (scol >> 1);
    GLDS(ksrc, (char*)&Klds[0][0] + tid * 16);
    GLDS(ksrc + (size_t)32 * QKS, (char*)&Klds[0][0] + 4096 + tid * 16);
    const __bf16* vsrc = Vt + (size_t)srow * T_SEQ + (scol >> 1);
    GLDS(vsrc, (char*)&Vlds[0][0] + tid * 16);
    GLDS(vsrc + (size_t)32 * T_SEQ, (char*)&Vlds[0][0] + 4096 + tid * 16);
  }
  __syncthreads();

  const __bf16* kstage = Kg + (size_t)(64 + srow) * QKS + (scol >> 1);
  const __bf16* vstage = Vt + (size_t)srow * T_SEQ + 64 + (scol >> 1);

#pragma unroll 1
  for (int kb = 0; kb < nkb; ++kb) {
    const int cur = kb & 1;
    if (kb + 1 < nkb) {
      GLDS(kstage, (char*)&Klds[cur ^ 1][0] + tid * 16);
      GLDS(kstage + (size_t)32 * QKS, (char*)&Klds[cur ^ 1][0] + 4096 + tid * 16);
      GLDS(vstage, (char*)&Vlds[cur ^ 1][0] + tid * 16);
      GLDS(vstage + (size_t)32 * T_SEQ, (char*)&Vlds[cur ^ 1][0] + 4096 + tid * 16);
      kstage += (size_t)64 * QKS;
      vstage += 64;
    }

    // QK^T: S^T[kv][q]; kk outer -> 8 independent MFMAs per kk sweep
    f32x4 s[2][4] = {};
    const char* Kb = (const char*)&Klds[cur][0];
#pragma unroll
    for (int kk = 0; kk < 2; ++kk) {
#pragma unroll
      for (int st = 0; st < 4; ++st) {
        const char* rowp = Kb + (st * 16 + l16) * 128;
        bf16x8 kf = *(const bf16x8*)(rowp + ((kk * 64 + g * 16) ^ swz));
        s[0][st] = MFMA16(kf, qf[0][kk], s[0][st]);
        s[1][st] = MFMA16(kf, qf[1][kk], s[1][st]);
      }
    }
    // causal mask: only the last two KV tiles (block-uniform branch)
    if (kb >= 2 * qt) {
      const int kvbase = (kb - 2 * qt) * 64;
#pragma unroll
      for (int qg = 0; qg < 2; ++qg) {
        const int qloc = wave * 32 + qg * 16 + l16;
#pragma unroll
        for (int st = 0; st < 4; ++st)
#pragma unroll
          for (int r = 0; r < 4; ++r)
            if (kvbase + st * 16 + g * 4 + r > qloc) s[qg][st][r] = NEG;
      }
    }
    // softmax numerator: p = exp2(s) (Q pre-scaled by 0.125*log2e)
#pragma unroll
    for (int qg = 0; qg < 2; ++qg) {
      char* Pr = Pw + (qg * 16 + l16) * 128;
#pragma unroll
      for (int st = 0; st < 4; ++st) {
        bf16x4 pb;
#pragma unroll
        for (int r = 0; r < 4; ++r)
          pb[r] = (__bf16)__builtin_amdgcn_exp2f(s[qg][st][r]);
        *(bf16x4*)(Pr + ((st * 32 + g * 8) ^ swz)) = pb;
      }
    }

    // PV: each vf feeds 2 MFMAs; row-sum via ones-MFMA
    const char* Vb = (const char*)&Vlds[cur][0];
#pragma unroll
    for (int hf = 0; hf < 2; ++hf) {
      bf16x8 pf0 = *(const bf16x8*)(Pw + (l16)       * 128 + ((hf * 64 + g * 16) ^ swz));
      bf16x8 pf1 = *(const bf16x8*)(Pw + (16 + l16)  * 128 + ((hf * 64 + g * 16) ^ swz));
      o_l[0] = MFMA16(ones, pf0, o_l[0]);
      o_l[1] = MFMA16(ones, pf1, o_l[1]);
#pragma unroll
      for (int dt = 0; dt < 4; ++dt) {
        bf16x8 vf = *(const bf16x8*)(Vb + (dt * 16 + l16) * 128 + ((hf * 64 + g * 16) ^ swz));
        o[0][dt] = MFMA16(vf, pf0, o[0][dt]);
        o[1][dt] = MFMA16(vf, pf1, o[1][dt]);
      }
    }
    __syncthreads();   // drains prefetch vmcnt (issued a full tile ago)
  }

#pragma unroll
  for (int qg = 0; qg < 2; ++qg) {
    const float inv_l = 1.0f / o_l[qg][0];
    const int qrow = qbase + qg * 16 + l16;
#pragma unroll
    for (int dt = 0; dt < 4; ++dt)
#pragma unroll
      for (int r = 0; r < 4; ++r)
        y[((size_t)b * T_SEQ + qrow) * CDIM + h * DH + dt * 16 + g * 4 + r] =
            (__bf16)(o[qg][dt][r] * inv_l);
  }
}

// ---------------- launch ----------------
extern "C" void kernel_launch(void* const* d_in, const int* in_sizes, int n_in,
                              void* d_out, int out_size, void* d_ws, size_t ws_size,
                              hipStream_t stream) {
  const float* x      = (const float*)d_in[0];   // [4,2048,1024]
  const float* w_qkv  = (const float*)d_in[1];   // [1024,3072]
  const float* w_proj = (const float*)d_in[2];   // [1024,1024]
  float* out = (float*)d_out;                    // [4,2048,1024]

  __bf16* xb     = (__bf16*)d_ws;                // 8192*1024
  __bf16* wqkvT  = xb + 8388608;                 // 3072*1024
  __bf16* wprojT = wqkvT + 3145728;              // 1024*1024
  __bf16* qk     = wprojT + 1048576;             // 8192*2048 (q|k)
  __bf16* VT     = qk + 16777216;                // 4*1024*2048 (V transposed)
  __bf16* yb     = VT + 8388608;                 // 8192*1024

  const float SCF = 0.125f * 1.44269504088896340736f;  // softmax scale * log2(e)

  cast_f32_bf16_kernel<<<8192, 256, 0, stream>>>(x, xb, 2097152);
  transpose_cast_kernel<<<dim3(96, 32), dim3(32, 8), 0, stream>>>(w_qkv, wqkvT, 1024, 3072, SCF, 1024);
  transpose_cast_kernel<<<dim3(32, 32), dim3(32, 8), 0, stream>>>(w_proj, wprojT, 1024, 1024, 1.0f, 0);
  gemm1_kernel<<<1536, 256, 0, stream>>>(xb, wqkvT, qk, VT);
  attn_kernel<<<1024, 256, 0, stream>>>(qk, VT, yb);
  gemm2_kernel<<<256, 512, 0, stream>>>(yb, wprojT, out);
}

// Round 19
// 153.618 us; speedup vs baseline: 1.0353x; 1.0353x over previous
//
#include <hip/hip_runtime.h>
#include <hip/hip_bf16.h>

typedef __bf16 bf16x8 __attribute__((ext_vector_type(8)));
typedef __bf16 bf16x4 __attribute__((ext_vector_type(4)));
typedef float  f32x4  __attribute__((ext_vector_type(4)));

#define MFMA16(a,b,c) __builtin_amdgcn_mfma_f32_16x16x32_bf16((a),(b),(c),0,0,0)

#define T_SEQ 2048
#define CDIM  1024
#define NH    16
#define DH    64
#define C3    3072
#define QKS   2048   // qk buffer row stride: [q 1024 | k 1024]

// async global->LDS, 16B per lane; LDS dest must be wave-uniform base + lane*16
#define GLDS(g, l) __builtin_amdgcn_global_load_lds( \
    (const __attribute__((address_space(1))) void*)(g), \
    (__attribute__((address_space(3))) void*)(l), 16, 0, 0)

// ---------------- cast f32 -> bf16, vectorized ----------------
__global__ void cast_f32_bf16_kernel(const float* __restrict__ in,
                                     __bf16* __restrict__ out, int n4) {
  int i = blockIdx.x * 256 + threadIdx.x;
  if (i >= n4) return;
  f32x4 v = ((const f32x4*)in)[i];
  bf16x4 o;
  o[0] = (__bf16)v[0]; o[1] = (__bf16)v[1];
  o[2] = (__bf16)v[2]; o[3] = (__bf16)v[3];
  ((bf16x4*)out)[i] = o;
}

// ---- transpose + cast: W[R][C] f32 -> WT[C][R] bf16; rows c<qcols scaled ----
__global__ void transpose_cast_kernel(const float* __restrict__ W,
                                      __bf16* __restrict__ WT, int R, int C,
                                      float qscale, int qcols) {
  __shared__ float tile[32][33];
  int c0 = blockIdx.x * 32, r0 = blockIdx.y * 32;
  int tx = threadIdx.x, ty = threadIdx.y;
#pragma unroll
  for (int i = 0; i < 32; i += 8)
    tile[ty + i][tx] = W[(size_t)(r0 + ty + i) * C + c0 + tx];
  __syncthreads();
#pragma unroll
  for (int i = 0; i < 32; i += 8) {
    int c = c0 + ty + i;
    float sc = (c < qcols) ? qscale : 1.0f;
    WT[(size_t)c * R + r0 + tx] = (__bf16)(tile[tx][ty + i] * sc);
  }
}

// ------- GEMM1: 128x128 4-phase bf16 GEMM, 64KB LDS => 2 blocks/CU ---------
__global__ __launch_bounds__(256, 2)
void gemm1_kernel(const __bf16* __restrict__ A, const __bf16* __restrict__ BT,
                  __bf16* __restrict__ qkp, __bf16* __restrict__ VTp) {
  __shared__ __align__(16) __bf16 S[2][2][128 * 64];  // [buf][A/B] 64KB
  const int K = 1024;
  const int tid  = threadIdx.x;
  const int lane = tid & 63;
  const int g    = lane >> 4;
  const int l16  = lane & 15;
  const int wave = tid >> 6;
  const int wm   = wave >> 1;
  const int wn   = wave & 1;

  const int sb = (blockIdx.x & 7) * 192 + (blockIdx.x >> 3);
  const int bn = sb % 24;
  const int bm = sb / 24;

  const int srow = tid >> 3;
  const int scol = ((tid & 7) << 4) ^ ((srow & 7) << 4);
  const int swz  = (l16 & 7) << 4;

  const __bf16* Abase = A  + (size_t)(bm * 128 + srow) * K + (scol >> 1);
  const __bf16* Bbase = BT + (size_t)(bn * 128 + srow) * K + (scol >> 1);

  f32x4  acc[4][4] = {};
  bf16x8 ar[2][2];
  bf16x8 br[4][2];

#define STAGE_A(BUF, K0) do { \
    _Pragma("unroll") for (int u_ = 0; u_ < 4; ++u_) \
      GLDS(Abase + (size_t)u_ * 32 * K + (K0), (char*)&S[BUF][0][0] + u_ * 4096 + tid * 16); \
  } while (0)
#define STAGE_B(BUF, K0) do { \
    _Pragma("unroll") for (int u_ = 0; u_ < 4; ++u_) \
      GLDS(Bbase + (size_t)u_ * 32 * K + (K0), (char*)&S[BUF][1][0] + u_ * 4096 + tid * 16); \
  } while (0)

#define LDA(BUF, IH) do { \
    const char* ab_ = (const char*)&S[BUF][0][0]; \
    _Pragma("unroll") for (int i_ = 0; i_ < 2; ++i_) { \
      const char* rp_ = ab_ + (wm * 64 + (IH) * 32 + i_ * 16 + l16) * 128; \
      _Pragma("unroll") for (int kk_ = 0; kk_ < 2; ++kk_) \
        ar[i_][kk_] = *(const bf16x8*)(rp_ + ((kk_ * 64 + g * 16) ^ swz)); \
    } \
  } while (0)

#define LDB(BUF) do { \
    const char* bb_ = (const char*)&S[BUF][1][0]; \
    _Pragma("unroll") for (int j_ = 0; j_ < 4; ++j_) { \
      const char* rp_ = bb_ + (wn * 64 + j_ * 16 + l16) * 128; \
      _Pragma("unroll") for (int kk_ = 0; kk_ < 2; ++kk_) \
        br[j_][kk_] = *(const bf16x8*)(rp_ + ((kk_ * 64 + g * 16) ^ swz)); \
    } \
  } while (0)

#define MQ(IH) do { \
    __builtin_amdgcn_s_setprio(1); \
    _Pragma("unroll") for (int kk_ = 0; kk_ < 2; ++kk_) \
      _Pragma("unroll") for (int i_ = 0; i_ < 2; ++i_) \
        _Pragma("unroll") for (int j_ = 0; j_ < 4; ++j_) \
          acc[(IH) * 2 + i_][j_] = \
              MFMA16(ar[i_][kk_], br[j_][kk_], acc[(IH) * 2 + i_][j_]); \
    __builtin_amdgcn_s_setprio(0); \
  } while (0)

#define SBAR do { \
    __builtin_amdgcn_sched_barrier(0); \
    __builtin_amdgcn_s_barrier(); \
    __builtin_amdgcn_sched_barrier(0); \
  } while (0)

  STAGE_A(0, 0); STAGE_B(0, 0);
  asm volatile("s_waitcnt vmcnt(0)" ::: "memory");
  SBAR;

  const int NIT = K >> 7;
#pragma unroll 1
  for (int it = 0; it < NIT; ++it) {
    const int kt1 = (2 * it + 1) << 6;
    const int kt2 = (2 * it + 2) << 6;
    const bool stg = (it + 1) < NIT;

    LDA(0, 0); LDB(0);
    STAGE_A(1, kt1); STAGE_B(1, kt1);
    SBAR; MQ(0); SBAR;

    LDA(0, 1);
    asm volatile("s_waitcnt vmcnt(0)" ::: "memory");
    SBAR; MQ(1); SBAR;

    LDA(1, 0); LDB(1);
    if (stg) { STAGE_A(0, kt2); STAGE_B(0, kt2); }
    SBAR; MQ(0); SBAR;

    LDA(1, 1);
    asm volatile("s_waitcnt vmcnt(0)" ::: "memory");
    SBAR; MQ(1); SBAR;
  }

  if (bn < 16) {
#pragma unroll
    for (int a = 0; a < 4; ++a) {
      const int row0 = bm * 128 + wm * 64 + a * 16 + g * 4;
#pragma unroll
      for (int jj = 0; jj < 4; ++jj) {
        const int col = bn * 128 + wn * 64 + jj * 16 + l16;
#pragma unroll
        for (int r = 0; r < 4; ++r)
          qkp[(size_t)(row0 + r) * QKS + col] = (__bf16)acc[a][jj][r];
      }
    }
  } else {
#pragma unroll
    for (int a = 0; a < 4; ++a) {
      const int row0 = bm * 128 + wm * 64 + a * 16 + g * 4;
      const int b    = row0 >> 11;
      const int t0   = row0 & 2047;
#pragma unroll
      for (int jj = 0; jj < 4; ++jj) {
        const int c = (bn - 16) * 128 + wn * 64 + jj * 16 + l16;
        bf16x4 pb;
#pragma unroll
        for (int r = 0; r < 4; ++r) pb[r] = (__bf16)acc[a][jj][r];
        *(bf16x4*)(VTp + ((size_t)((b << 10) + c)) * T_SEQ + t0) = pb;
      }
    }
  }
#undef STAGE_A
#undef STAGE_B
#undef LDA
#undef LDB
#undef MQ
#undef SBAR
}

// ---------------- GEMM2: 256x128 4-phase bf16 GEMM, f32 out ----------------
__global__ __launch_bounds__(512, 1)
void gemm2_kernel(const __bf16* __restrict__ A, const __bf16* __restrict__ BT,
                  float* __restrict__ Cout) {
  __shared__ __align__(16) __bf16 S[2][3][128 * 64];  // [buf][A-lo,A-hi,B] 96KB
  const int tid  = threadIdx.x;
  const int lane = tid & 63;
  const int g    = lane >> 4;
  const int l16  = lane & 15;
  const int wave = tid >> 6;
  const int wm   = wave >> 2;
  const int wn   = wave & 3;

  const int K = 1024;
  const int sb = (blockIdx.x & 7) * 32 + (blockIdx.x >> 3);
  const int bn = sb & 7;
  const int bm = sb >> 3;

  const int srow = tid >> 3;
  const int scol = ((tid & 7) << 4) ^ ((srow & 7) << 4);
  const int swz  = (l16 & 7) << 4;

  const __bf16* Abase = A  + (size_t)(bm * 256 + srow) * K + (scol >> 1);
  const __bf16* Bbase = BT + (size_t)(bn * 128 + srow) * K + (scol >> 1);

  f32x4  acc[8][2] = {};
  bf16x8 ar[4][2];
  bf16x8 br[2][2];

#define STAGE2(BUF, U, K0) do { \
    const __bf16* sp_ = ((U) < 2 ? Abase + (size_t)(U) * 128 * K : Bbase) + (K0); \
    char* dp_ = (char*)&S[BUF][U][0] + tid * 16; \
    GLDS(sp_, dp_); \
    GLDS(sp_ + (size_t)64 * K, dp_ + 8192); \
  } while (0)

#define LDA2(BUF, MH) do { \
    const char* ab_ = (const char*)&S[BUF][wm][0]; \
    _Pragma("unroll") for (int i_ = 0; i_ < 4; ++i_) { \
      const char* rp_ = ab_ + ((MH) * 64 + i_ * 16 + l16) * 128; \
      _Pragma("unroll") for (int kk_ = 0; kk_ < 2; ++kk_) \
        ar[i_][kk_] = *(const bf16x8*)(rp_ + ((kk_ * 64 + g * 16) ^ swz)); \
    } \
  } while (0)

#define LDB2(BUF) do { \
    const char* bb_ = (const char*)&S[BUF][2][0]; \
    _Pragma("unroll") for (int j_ = 0; j_ < 2; ++j_) { \
      const char* rp_ = bb_ + (wn * 32 + j_ * 16 + l16) * 128; \
      _Pragma("unroll") for (int kk_ = 0; kk_ < 2; ++kk_) \
        br[j_][kk_] = *(const bf16x8*)(rp_ + ((kk_ * 64 + g * 16) ^ swz)); \
    } \
  } while (0)

#define MQ2(MH) do { \
    __builtin_amdgcn_s_setprio(1); \
    _Pragma("unroll") for (int kk_ = 0; kk_ < 2; ++kk_) \
      _Pragma("unroll") for (int i_ = 0; i_ < 4; ++i_) \
        _Pragma("unroll") for (int j_ = 0; j_ < 2; ++j_) \
          acc[(MH) * 4 + i_][j_] = \
              MFMA16(ar[i_][kk_], br[j_][kk_], acc[(MH) * 4 + i_][j_]); \
    __builtin_amdgcn_s_setprio(0); \
  } while (0)

#define SBAR2 do { \
    __builtin_amdgcn_sched_barrier(0); \
    __builtin_amdgcn_s_barrier(); \
    __builtin_amdgcn_sched_barrier(0); \
  } while (0)

  STAGE2(0, 0, 0); STAGE2(0, 1, 0); STAGE2(0, 2, 0);
  STAGE2(1, 0, 64);
  asm volatile("s_waitcnt vmcnt(2)" ::: "memory");
  SBAR2;

  const int NIT = K >> 7;
#pragma unroll 1
  for (int it = 0; it < NIT; ++it) {
    const int k1 = (2 * it + 1) << 6;
    const int k2 = (2 * it + 2) << 6;
    const int k3 = (2 * it + 3) << 6;
    const bool stg = (it + 1) < NIT;

    LDA2(0, 0); LDB2(0);
    STAGE2(1, 1, k1); STAGE2(1, 2, k1);
    SBAR2; MQ2(0); SBAR2;

    LDA2(0, 1);
    if (stg) {
      STAGE2(0, 0, k2);
      asm volatile("s_waitcnt vmcnt(2)" ::: "memory");
    } else {
      asm volatile("s_waitcnt vmcnt(0)" ::: "memory");
    }
    SBAR2; MQ2(1); SBAR2;

    LDA2(1, 0); LDB2(1);
    if (stg) { STAGE2(0, 1, k2); STAGE2(0, 2, k2); }
    SBAR2; MQ2(0); SBAR2;

    LDA2(1, 1);
    if (stg) {
      STAGE2(1, 0, k3);
      asm volatile("s_waitcnt vmcnt(2)" ::: "memory");
    }
    SBAR2; MQ2(1); SBAR2;
  }

#pragma unroll
  for (int ii = 0; ii < 8; ++ii) {
    const int row0 = bm * 256 + wm * 128 + ii * 16 + g * 4;
#pragma unroll
    for (int jj = 0; jj < 2; ++jj) {
      const int col = bn * 128 + wn * 32 + jj * 16 + l16;
#pragma unroll
      for (int r = 0; r < 4; ++r)
        Cout[(size_t)(row0 + r) * 1024 + col] = acc[ii][jj][r];
    }
  }
#undef STAGE2
#undef LDA2
#undef LDB2
#undef MQ2
#undef SBAR2
}

// ------- causal flash attention, QBLK=128, paired blocks, SW-PIPELINED ------
// Iteration kb runs {QK(kb) + softmax(kb)} AND PV(kb-1): independent work on
// MFMA vs VALU pipes, interleaved by the compiler. V is triple-buffered
// (stage kb+1 -> (kb+1)%3 while PV reads (kb-1)%3: differ by 2 mod 3); K
// double-buffered; P has 2 per-wave slots (write kb&1, read (kb-1)&1).
// LDS 72KB -> 2 blocks/CU. Paired grid (qt = p / 15-p) = 512 blocks.
__global__ __launch_bounds__(256)
void attn_kernel(const __bf16* __restrict__ qk, const __bf16* __restrict__ VT,
                 __bf16* __restrict__ y) {
  __shared__ __align__(16) __bf16 Klds[2][64 * 64];       // 16KB
  __shared__ __align__(16) __bf16 Vlds[3][64 * 64];       // 24KB
  __shared__ __align__(16) __bf16 Plds[4][2][32 * 64];    // 32KB
  const int tid  = threadIdx.x;
  const int lane = tid & 63;
  const int g    = lane >> 4;
  const int l16  = lane & 15;
  const int wave = tid >> 6;

  const int pairid = blockIdx.x >> 6;   // 0..7
  const int bh     = blockIdx.x & 63;   // XCD-local decode
  const int h      = bh & (NH - 1);
  const int b      = bh >> 4;

  const __bf16* Qg = qk + (size_t)b * T_SEQ * QKS + h * DH;
  const __bf16* Kg = Qg + 1024;
  const __bf16* Vt = VT + ((size_t)(b << 10) + h * DH) * T_SEQ;

  const int srow = tid >> 3;
  const int scol = ((tid & 7) * 16) ^ ((srow & 7) << 4);
  const int swz  = (l16 & 7) << 4;

  const float NEG = -3.0e38f;

  bf16x8 ones;
#pragma unroll
  for (int j = 0; j < 8; ++j) ones[j] = (__bf16)1.0f;

  // stage K tile T into buf KB, V tile T into buf VB
#define STAGE_KV(T, KB, VB) do { \
    const __bf16* ks_ = Kg + (size_t)((T) * 64 + srow) * QKS + (scol >> 1); \
    GLDS(ks_, (char*)&Klds[KB][0] + tid * 16); \
    GLDS(ks_ + (size_t)32 * QKS, (char*)&Klds[KB][0] + 4096 + tid * 16); \
    const __bf16* vs_ = Vt + (size_t)srow * T_SEQ + (T) * 64 + (scol >> 1); \
    GLDS(vs_, (char*)&Vlds[VB][0] + tid * 16); \
    GLDS(vs_ + (size_t)32 * T_SEQ, (char*)&Vlds[VB][0] + 4096 + tid * 16); \
  } while (0)

  // QK(kb) from Klds[KB] + mask + softmax -> P slot PS
#define QKSM(KB, PS, KB_IDX, QT) do { \
    f32x4 s[2][4] = {}; \
    const char* Kb_ = (const char*)&Klds[KB][0]; \
    _Pragma("unroll") for (int kk = 0; kk < 2; ++kk) { \
      _Pragma("unroll") for (int st = 0; st < 4; ++st) { \
        const char* rowp = Kb_ + (st * 16 + l16) * 128; \
        bf16x8 kf = *(const bf16x8*)(rowp + ((kk * 64 + g * 16) ^ swz)); \
        s[0][st] = MFMA16(kf, qf[0][kk], s[0][st]); \
        s[1][st] = MFMA16(kf, qf[1][kk], s[1][st]); \
      } \
    } \
    if ((KB_IDX) >= 2 * (QT)) { \
      const int kvbase = ((KB_IDX) - 2 * (QT)) * 64; \
      _Pragma("unroll") for (int qg = 0; qg < 2; ++qg) { \
        const int qloc = wave * 32 + qg * 16 + l16; \
        _Pragma("unroll") for (int st = 0; st < 4; ++st) \
          _Pragma("unroll") for (int r = 0; r < 4; ++r) \
            if (kvbase + st * 16 + g * 4 + r > qloc) s[qg][st][r] = NEG; \
      } \
    } \
    char* Pw_ = (char*)&Plds[wave][PS][0]; \
    _Pragma("unroll") for (int qg = 0; qg < 2; ++qg) { \
      char* Pr_ = Pw_ + (qg * 16 + l16) * 128; \
      _Pragma("unroll") for (int st = 0; st < 4; ++st) { \
        bf16x4 pb; \
        _Pragma("unroll") for (int r = 0; r < 4; ++r) \
          pb[r] = (__bf16)__builtin_amdgcn_exp2f(s[qg][st][r]); \
        *(bf16x4*)(Pr_ + ((st * 32 + g * 8) ^ swz)) = pb; \
      } \
    } \
  } while (0)

  // PV from Vlds[VB] and P slot PS -> o, o_l
#define PV(VB, PS) do { \
    const char* Vb_ = (const char*)&Vlds[VB][0]; \
    const char* Pw_ = (const char*)&Plds[wave][PS][0]; \
    _Pragma("unroll") for (int hf = 0; hf < 2; ++hf) { \
      bf16x8 pf0 = *(const bf16x8*)(Pw_ + (l16)      * 128 + ((hf * 64 + g * 16) ^ swz)); \
      bf16x8 pf1 = *(const bf16x8*)(Pw_ + (16 + l16) * 128 + ((hf * 64 + g * 16) ^ swz)); \
      o_l[0] = MFMA16(ones, pf0, o_l[0]); \
      o_l[1] = MFMA16(ones, pf1, o_l[1]); \
      _Pragma("unroll") for (int dt = 0; dt < 4; ++dt) { \
        bf16x8 vf = *(const bf16x8*)(Vb_ + (dt * 16 + l16) * 128 + ((hf * 64 + g * 16) ^ swz)); \
        o[0][dt] = MFMA16(vf, pf0, o[0][dt]); \
        o[1][dt] = MFMA16(vf, pf1, o[1][dt]); \
      } \
    } \
  } while (0)

#pragma unroll 1
  for (int ph = 0; ph < 2; ++ph) {
    const int qt    = ph ? (15 - pairid) : pairid;   // 128-row q tile
    const int qbase = qt * 128 + wave * 32;          // wave's first q row

    bf16x8 qf[2][2];
#pragma unroll
    for (int qg = 0; qg < 2; ++qg)
#pragma unroll
      for (int kk = 0; kk < 2; ++kk)
        qf[qg][kk] = *(const bf16x8*)(Qg + (size_t)(qbase + qg * 16 + l16) * QKS + kk * 32 + g * 8);

    f32x4 o[2][4] = {};
    f32x4 o_l[2]  = {};

    const int nkb = 2 * qt + 2;

    __syncthreads();                 // fence prev phase's epilogue readers
    STAGE_KV(0, 0, 0);
    __syncthreads();                 // tile 0 resident (drain + barrier)
    if (nkb > 1) STAGE_KV(1, 1, 1);  // issued early, drained by next barrier
    QKSM(0, 0, 0, qt);               // QK + softmax of tile 0
    __syncthreads();                 // tile 1 resident; fences buffers

#pragma unroll 1
    for (int kb = 1; kb < nkb; ++kb) {
      if (kb + 1 < nkb) STAGE_KV(kb + 1, (kb + 1) & 1, (kb + 1) % 3);
      QKSM(kb & 1, kb & 1, kb, qt);  // QK+softmax(kb)  (VALU-heavy)
      PV((kb - 1) % 3, (kb - 1) & 1);// PV(kb-1)        (MFMA-heavy, independent)
      __syncthreads();               // drains stage(kb+1); fences rotation
    }
    // epilogue: PV of the last tile
    PV((nkb - 1) % 3, (nkb - 1) & 1);

#pragma unroll
    for (int qg = 0; qg < 2; ++qg) {
      const float inv_l = 1.0f / o_l[qg][0];
      const int qrow = qbase + qg * 16 + l16;
#pragma unroll
      for (int dt = 0; dt < 4; ++dt)
#pragma unroll
        for (int r = 0; r < 4; ++r)
          y[((size_t)b * T_SEQ + qrow) * CDIM + h * DH + dt * 16 + g * 4 + r] =
              (__bf16)(o[qg][dt][r] * inv_l);
    }
  }
#undef STAGE_KV
#undef QKSM
#undef PV
}

// ---------------- launch ----------------
extern "C" void kernel_launch(void* const* d_in, const int* in_sizes, int n_in,
                              void* d_out, int out_size, void* d_ws, size_t ws_size,
                              hipStream_t stream) {
  const float* x      = (const float*)d_in[0];   // [4,2048,1024]
  const float* w_qkv  = (const float*)d_in[1];   // [1024,3072]
  const float* w_proj = (const float*)d_in[2];   // [1024,1024]
  float* out = (float*)d_out;                    // [4,2048,1024]

  __bf16* xb     = (__bf16*)d_ws;                // 8192*1024
  __bf16* wqkvT  = xb + 8388608;                 // 3072*1024
  __bf16* wprojT = wqkvT + 3145728;              // 1024*1024
  __bf16* qk     = wprojT + 1048576;             // 8192*2048 (q|k)
  __bf16* VT     = qk + 16777216;                // 4*1024*2048 (V transposed)
  __bf16* yb     = VT + 8388608;                 // 8192*1024

  const float SCF = 0.125f * 1.44269504088896340736f;  // softmax scale * log2(e)

  cast_f32_bf16_kernel<<<8192, 256, 0, stream>>>(x, xb, 2097152);
  transpose_cast_kernel<<<dim3(96, 32), dim3(32, 8), 0, stream>>>(w_qkv, wqkvT, 1024, 3072, SCF, 1024);
  transpose_cast_kernel<<<dim3(32, 32), dim3(32, 8), 0, stream>>>(w_proj, wprojT, 1024, 1024, 1.0f, 0);
  gemm1_kernel<<<1536, 256, 0, stream>>>(xb, wqkvT, qk, VT);
  attn_kernel<<<512, 256, 0, stream>>>(qk, VT, yb);
  gemm2_kernel<<<256, 512, 0, stream>>>(yb, wprojT, out);
}

// Round 20
// 152.249 us; speedup vs baseline: 1.0446x; 1.0090x over previous
//
#include <hip/hip_runtime.h>
#include <hip/hip_bf16.h>

typedef __bf16 bf16x8 __attribute__((ext_vector_type(8)));
typedef __bf16 bf16x4 __attribute__((ext_vector_type(4)));
typedef float  f32x4  __attribute__((ext_vector_type(4)));

#define MFMA16(a,b,c) __builtin_amdgcn_mfma_f32_16x16x32_bf16((a),(b),(c),0,0,0)

#define T_SEQ 2048
#define CDIM  1024
#define NH    16
#define DH    64
#define C3    3072
#define QKS   2048   // qk buffer row stride: [q 1024 | k 1024]

// async global->LDS, 16B per lane; LDS dest must be wave-uniform base + lane*16
#define GLDS(g, l) __builtin_amdgcn_global_load_lds( \
    (const __attribute__((address_space(1))) void*)(g), \
    (__attribute__((address_space(3))) void*)(l), 16, 0, 0)

// ---------------- cast f32 -> bf16, vectorized ----------------
__global__ void cast_f32_bf16_kernel(const float* __restrict__ in,
                                     __bf16* __restrict__ out, int n4) {
  int i = blockIdx.x * 256 + threadIdx.x;
  if (i >= n4) return;
  f32x4 v = ((const f32x4*)in)[i];
  bf16x4 o;
  o[0] = (__bf16)v[0]; o[1] = (__bf16)v[1];
  o[2] = (__bf16)v[2]; o[3] = (__bf16)v[3];
  ((bf16x4*)out)[i] = o;
}

// ---- transpose + cast: W[R][C] f32 -> WT[C][R] bf16; rows c<qcols scaled ----
__global__ void transpose_cast_kernel(const float* __restrict__ W,
                                      __bf16* __restrict__ WT, int R, int C,
                                      float qscale, int qcols) {
  __shared__ float tile[32][33];
  int c0 = blockIdx.x * 32, r0 = blockIdx.y * 32;
  int tx = threadIdx.x, ty = threadIdx.y;
#pragma unroll
  for (int i = 0; i < 32; i += 8)
    tile[ty + i][tx] = W[(size_t)(r0 + ty + i) * C + c0 + tx];
  __syncthreads();
#pragma unroll
  for (int i = 0; i < 32; i += 8) {
    int c = c0 + ty + i;
    float sc = (c < qcols) ? qscale : 1.0f;
    WT[(size_t)c * R + r0 + tx] = (__bf16)(tile[tx][ty + i] * sc);
  }
}

// ------ 128x128 4-phase bf16 GEMM, 64KB LDS => 2 blocks/CU (proven) --------
// MODE 1 (GEMM1): grid 1536, nbn=24; bn<16 -> bf16 qk[row][2048], bn>=16 ->
// V transposed into VT[b][c][t]. MODE 0 (GEMM2): grid 512, nbn=8; f32 out
// [8192,1024]. Same body: XCD-contiguous + L2-chunk decode, GLDS staging
// with both-sides XOR swizzle, 4 phases x 16 MFMA, vmcnt(0) residency waits
// (co-resident block fills the stall -- round-17 proven).
template <int MODE>
__global__ __launch_bounds__(256, 2)
void gemm12_kernel(const __bf16* __restrict__ A, const __bf16* __restrict__ BT,
                   void* __restrict__ Cout, __bf16* __restrict__ VTp, int nbn) {
  __shared__ __align__(16) __bf16 S[2][2][128 * 64];  // [buf][A/B] 64KB
  const int K = 1024;
  const int tid  = threadIdx.x;
  const int lane = tid & 63;
  const int g    = lane >> 4;
  const int l16  = lane & 15;
  const int wave = tid >> 6;
  const int wm   = wave >> 1;
  const int wn   = wave & 1;

  const int sb = (blockIdx.x & 7) * ((int)gridDim.x >> 3) + (blockIdx.x >> 3);
  const int bn = sb % nbn;
  const int bm = sb / nbn;

  const int srow = tid >> 3;
  const int scol = ((tid & 7) << 4) ^ ((srow & 7) << 4);
  const int swz  = (l16 & 7) << 4;

  const __bf16* Abase = A  + (size_t)(bm * 128 + srow) * K + (scol >> 1);
  const __bf16* Bbase = BT + (size_t)(bn * 128 + srow) * K + (scol >> 1);

  f32x4  acc[4][4] = {};
  bf16x8 ar[2][2];
  bf16x8 br[4][2];

#define STAGE_A(BUF, K0) do { \
    _Pragma("unroll") for (int u_ = 0; u_ < 4; ++u_) \
      GLDS(Abase + (size_t)u_ * 32 * K + (K0), (char*)&S[BUF][0][0] + u_ * 4096 + tid * 16); \
  } while (0)
#define STAGE_B(BUF, K0) do { \
    _Pragma("unroll") for (int u_ = 0; u_ < 4; ++u_) \
      GLDS(Bbase + (size_t)u_ * 32 * K + (K0), (char*)&S[BUF][1][0] + u_ * 4096 + tid * 16); \
  } while (0)

#define LDA(BUF, IH) do { \
    const char* ab_ = (const char*)&S[BUF][0][0]; \
    _Pragma("unroll") for (int i_ = 0; i_ < 2; ++i_) { \
      const char* rp_ = ab_ + (wm * 64 + (IH) * 32 + i_ * 16 + l16) * 128; \
      _Pragma("unroll") for (int kk_ = 0; kk_ < 2; ++kk_) \
        ar[i_][kk_] = *(const bf16x8*)(rp_ + ((kk_ * 64 + g * 16) ^ swz)); \
    } \
  } while (0)

#define LDB(BUF) do { \
    const char* bb_ = (const char*)&S[BUF][1][0]; \
    _Pragma("unroll") for (int j_ = 0; j_ < 4; ++j_) { \
      const char* rp_ = bb_ + (wn * 64 + j_ * 16 + l16) * 128; \
      _Pragma("unroll") for (int kk_ = 0; kk_ < 2; ++kk_) \
        br[j_][kk_] = *(const bf16x8*)(rp_ + ((kk_ * 64 + g * 16) ^ swz)); \
    } \
  } while (0)

#define MQ(IH) do { \
    __builtin_amdgcn_s_setprio(1); \
    _Pragma("unroll") for (int kk_ = 0; kk_ < 2; ++kk_) \
      _Pragma("unroll") for (int i_ = 0; i_ < 2; ++i_) \
        _Pragma("unroll") for (int j_ = 0; j_ < 4; ++j_) \
          acc[(IH) * 2 + i_][j_] = \
              MFMA16(ar[i_][kk_], br[j_][kk_], acc[(IH) * 2 + i_][j_]); \
    __builtin_amdgcn_s_setprio(0); \
  } while (0)

#define SBAR do { \
    __builtin_amdgcn_sched_barrier(0); \
    __builtin_amdgcn_s_barrier(); \
    __builtin_amdgcn_sched_barrier(0); \
  } while (0)

  STAGE_A(0, 0); STAGE_B(0, 0);
  asm volatile("s_waitcnt vmcnt(0)" ::: "memory");
  SBAR;

  const int NIT = K >> 7;
#pragma unroll 1
  for (int it = 0; it < NIT; ++it) {
    const int kt1 = (2 * it + 1) << 6;
    const int kt2 = (2 * it + 2) << 6;
    const bool stg = (it + 1) < NIT;

    LDA(0, 0); LDB(0);
    STAGE_A(1, kt1); STAGE_B(1, kt1);
    SBAR; MQ(0); SBAR;

    LDA(0, 1);
    asm volatile("s_waitcnt vmcnt(0)" ::: "memory");
    SBAR; MQ(1); SBAR;

    LDA(1, 0); LDB(1);
    if (stg) { STAGE_A(0, kt2); STAGE_B(0, kt2); }
    SBAR; MQ(0); SBAR;

    LDA(1, 1);
    asm volatile("s_waitcnt vmcnt(0)" ::: "memory");
    SBAR; MQ(1); SBAR;
  }

  // epilogue: D layout col=lane&15, row=(lane>>4)*4+reg
  if (MODE == 0) {
    // f32 out, N = 1024
#pragma unroll
    for (int a = 0; a < 4; ++a) {
      const int row0 = bm * 128 + wm * 64 + a * 16 + g * 4;
#pragma unroll
      for (int jj = 0; jj < 4; ++jj) {
        const int col = bn * 128 + wn * 64 + jj * 16 + l16;
#pragma unroll
        for (int r = 0; r < 4; ++r)
          ((float*)Cout)[(size_t)(row0 + r) * 1024 + col] = acc[a][jj][r];
      }
    }
  } else if (bn < 16) {
    // Q/K region: bf16 qk[row][2048]
#pragma unroll
    for (int a = 0; a < 4; ++a) {
      const int row0 = bm * 128 + wm * 64 + a * 16 + g * 4;
#pragma unroll
      for (int jj = 0; jj < 4; ++jj) {
        const int col = bn * 128 + wn * 64 + jj * 16 + l16;
#pragma unroll
        for (int r = 0; r < 4; ++r)
          ((__bf16*)Cout)[(size_t)(row0 + r) * QKS + col] = (__bf16)acc[a][jj][r];
      }
    }
  } else {
    // V region: write transposed into VT[b][c][t]; 4 contiguous t per lane
#pragma unroll
    for (int a = 0; a < 4; ++a) {
      const int row0 = bm * 128 + wm * 64 + a * 16 + g * 4;
      const int b    = row0 >> 11;
      const int t0   = row0 & 2047;
#pragma unroll
      for (int jj = 0; jj < 4; ++jj) {
        const int c = (bn - 16) * 128 + wn * 64 + jj * 16 + l16;
        bf16x4 pb;
#pragma unroll
        for (int r = 0; r < 4; ++r) pb[r] = (__bf16)acc[a][jj][r];
        *(bf16x4*)(VTp + ((size_t)((b << 10) + c)) * T_SEQ + t0) = pb;
      }
    }
  }
#undef STAGE_A
#undef STAGE_B
#undef LDA
#undef LDB
#undef MQ
#undef SBAR
}

// ---- causal flash attention, QBLK=128, paired blocks (round-17 best) ------
__global__ __launch_bounds__(256)
void attn_kernel(const __bf16* __restrict__ qk, const __bf16* __restrict__ VT,
                 __bf16* __restrict__ y) {
  __shared__ __align__(16) __bf16 Klds[2][64 * 64];
  __shared__ __align__(16) __bf16 Vlds[2][64 * 64];
  __shared__ __align__(16) __bf16 Plds[4][32 * 64];
  const int tid  = threadIdx.x;
  const int lane = tid & 63;
  const int g    = lane >> 4;
  const int l16  = lane & 15;
  const int wave = tid >> 6;

  const int pairid = blockIdx.x >> 6;   // 0..7
  const int bh     = blockIdx.x & 63;   // XCD-local decode
  const int h      = bh & (NH - 1);
  const int b      = bh >> 4;

  const __bf16* Qg = qk + (size_t)b * T_SEQ * QKS + h * DH;
  const __bf16* Kg = Qg + 1024;
  const __bf16* Vt = VT + ((size_t)(b << 10) + h * DH) * T_SEQ;

  const int srow = tid >> 3;
  const int scol = ((tid & 7) * 16) ^ ((srow & 7) << 4);
  const int swz  = (l16 & 7) << 4;

  const float NEG = -3.0e38f;

  bf16x8 ones;
#pragma unroll
  for (int j = 0; j < 8; ++j) ones[j] = (__bf16)1.0f;

  char* Pw = (char*)&Plds[wave][0];   // [32 q][64 kv] slab, rows 128B

#pragma unroll 1
  for (int ph = 0; ph < 2; ++ph) {
    const int qt    = ph ? (15 - pairid) : pairid;   // 128-row q tile
    const int qbase = qt * 128 + wave * 32;          // wave's first q row

    bf16x8 qf[2][2];
#pragma unroll
    for (int qg = 0; qg < 2; ++qg)
#pragma unroll
      for (int kk = 0; kk < 2; ++kk)
        qf[qg][kk] = *(const bf16x8*)(Qg + (size_t)(qbase + qg * 16 + l16) * QKS + kk * 32 + g * 8);

    f32x4 o[2][4] = {};
    f32x4 o_l[2]  = {};

    const int nkb = 2 * qt + 2;
    {   // prologue: stage tile 0 into buffer 0
      const __bf16* ksrc = Kg + (size_t)srow * QKS + (scol >> 1);
      GLDS(ksrc, (char*)&Klds[0][0] + tid * 16);
      GLDS(ksrc + (size_t)32 * QKS, (char*)&Klds[0][0] + 4096 + tid * 16);
      const __bf16* vsrc = Vt + (size_t)srow * T_SEQ + (scol >> 1);
      GLDS(vsrc, (char*)&Vlds[0][0] + tid * 16);
      GLDS(vsrc + (size_t)32 * T_SEQ, (char*)&Vlds[0][0] + 4096 + tid * 16);
    }
    __syncthreads();

    const __bf16* kstage = Kg + (size_t)(64 + srow) * QKS + (scol >> 1);
    const __bf16* vstage = Vt + (size_t)srow * T_SEQ + 64 + (scol >> 1);

#pragma unroll 1
    for (int kb = 0; kb < nkb; ++kb) {
      const int cur = kb & 1;
      if (kb + 1 < nkb) {
        GLDS(kstage, (char*)&Klds[cur ^ 1][0] + tid * 16);
        GLDS(kstage + (size_t)32 * QKS, (char*)&Klds[cur ^ 1][0] + 4096 + tid * 16);
        GLDS(vstage, (char*)&Vlds[cur ^ 1][0] + tid * 16);
        GLDS(vstage + (size_t)32 * T_SEQ, (char*)&Vlds[cur ^ 1][0] + 4096 + tid * 16);
        kstage += (size_t)64 * QKS;
        vstage += 64;
      }

      // QK^T: S^T[kv][q]; kk outer -> 8 independent MFMAs per kk sweep
      f32x4 s[2][4] = {};
      const char* Kb = (const char*)&Klds[cur][0];
#pragma unroll
      for (int kk = 0; kk < 2; ++kk) {
#pragma unroll
        for (int st = 0; st < 4; ++st) {
          const char* rowp = Kb + (st * 16 + l16) * 128;
          bf16x8 kf = *(const bf16x8*)(rowp + ((kk * 64 + g * 16) ^ swz));
          s[0][st] = MFMA16(kf, qf[0][kk], s[0][st]);
          s[1][st] = MFMA16(kf, qf[1][kk], s[1][st]);
        }
      }
      // causal mask: only the last two KV tiles (block-uniform branch)
      if (kb >= 2 * qt) {
        const int kvbase = (kb - 2 * qt) * 64;
#pragma unroll
        for (int qg = 0; qg < 2; ++qg) {
          const int qloc = wave * 32 + qg * 16 + l16;
#pragma unroll
          for (int st = 0; st < 4; ++st)
#pragma unroll
            for (int r = 0; r < 4; ++r)
              if (kvbase + st * 16 + g * 4 + r > qloc) s[qg][st][r] = NEG;
        }
      }
      // softmax numerator: p = exp2(s) (Q pre-scaled by 0.125*log2e)
#pragma unroll
      for (int qg = 0; qg < 2; ++qg) {
        char* Pr = Pw + (qg * 16 + l16) * 128;
#pragma unroll
        for (int st = 0; st < 4; ++st) {
          bf16x4 pb;
#pragma unroll
          for (int r = 0; r < 4; ++r)
            pb[r] = (__bf16)__builtin_amdgcn_exp2f(s[qg][st][r]);
          *(bf16x4*)(Pr + ((st * 32 + g * 8) ^ swz)) = pb;
        }
      }

      // PV: each vf feeds 2 MFMAs; row-sum via ones-MFMA
      const char* Vb = (const char*)&Vlds[cur][0];
#pragma unroll
      for (int hf = 0; hf < 2; ++hf) {
        bf16x8 pf0 = *(const bf16x8*)(Pw + (l16)       * 128 + ((hf * 64 + g * 16) ^ swz));
        bf16x8 pf1 = *(const bf16x8*)(Pw + (16 + l16)  * 128 + ((hf * 64 + g * 16) ^ swz));
        o_l[0] = MFMA16(ones, pf0, o_l[0]);
        o_l[1] = MFMA16(ones, pf1, o_l[1]);
#pragma unroll
        for (int dt = 0; dt < 4; ++dt) {
          bf16x8 vf = *(const bf16x8*)(Vb + (dt * 16 + l16) * 128 + ((hf * 64 + g * 16) ^ swz));
          o[0][dt] = MFMA16(vf, pf0, o[0][dt]);
          o[1][dt] = MFMA16(vf, pf1, o[1][dt]);
        }
      }
      __syncthreads();   // drains prefetch vmcnt (issued a full tile ago)
    }

#pragma unroll
    for (int qg = 0; qg < 2; ++qg) {
      const float inv_l = 1.0f / o_l[qg][0];
      const int qrow = qbase + qg * 16 + l16;
#pragma unroll
      for (int dt = 0; dt < 4; ++dt)
#pragma unroll
        for (int r = 0; r < 4; ++r)
          y[((size_t)b * T_SEQ + qrow) * CDIM + h * DH + dt * 16 + g * 4 + r] =
              (__bf16)(o[qg][dt][r] * inv_l);
    }
  }
}

// ---------------- launch ----------------
extern "C" void kernel_launch(void* const* d_in, const int* in_sizes, int n_in,
                              void* d_out, int out_size, void* d_ws, size_t ws_size,
                              hipStream_t stream) {
  const float* x      = (const float*)d_in[0];   // [4,2048,1024]
  const float* w_qkv  = (const float*)d_in[1];   // [1024,3072]
  const float* w_proj = (const float*)d_in[2];   // [1024,1024]
  float* out = (float*)d_out;                    // [4,2048,1024]

  __bf16* xb     = (__bf16*)d_ws;                // 8192*1024
  __bf16* wqkvT  = xb + 8388608;                 // 3072*1024
  __bf16* wprojT = wqkvT + 3145728;              // 1024*1024
  __bf16* qk     = wprojT + 1048576;             // 8192*2048 (q|k)
  __bf16* VT     = qk + 16777216;                // 4*1024*2048 (V transposed)
  __bf16* yb     = VT + 8388608;                 // 8192*1024

  const float SCF = 0.125f * 1.44269504088896340736f;  // softmax scale * log2(e)

  cast_f32_bf16_kernel<<<8192, 256, 0, stream>>>(x, xb, 2097152);
  transpose_cast_kernel<<<dim3(96, 32), dim3(32, 8), 0, stream>>>(w_qkv, wqkvT, 1024, 3072, SCF, 1024);
  transpose_cast_kernel<<<dim3(32, 32), dim3(32, 8), 0, stream>>>(w_proj, wprojT, 1024, 1024, 1.0f, 0);
  gemm12_kernel<1><<<1536, 256, 0, stream>>>(xb, wqkvT, (void*)qk, VT, 24);
  attn_kernel<<<512, 256, 0, stream>>>(qk, VT, yb);
  gemm12_kernel<0><<<512, 256, 0, stream>>>(yb, wprojT, (void*)out, nullptr, 8);
}